// Round 1
// baseline (1222.794 us; speedup 1.0000x reference)
//
#include <hip/hip_runtime.h>
#include <cstdint>
#include <cstddef>

typedef __bf16 bf16;
typedef __bf16 bf16x8 __attribute__((ext_vector_type(8)));
typedef float  f32x4  __attribute__((ext_vector_type(4)));

#define AS1 __attribute__((address_space(1)))
#define AS3 __attribute__((address_space(3)))

#define B_ 4
#define T_ 2048
#define C_ 1024
#define H_ 8
#define D_ 128
#define WIN_ 1024

// -------------------------------------------------------------------------
// f32 -> bf16 conversion (8 elems/thread, vectorized)
// -------------------------------------------------------------------------
__global__ void cvt_kernel(const float* __restrict__ src, bf16* __restrict__ dst, int n) {
  int i = (blockIdx.x * 256 + threadIdx.x) * 8;
  if (i >= n) return;
  float4 a = *(const float4*)(src + i);
  float4 b = *(const float4*)(src + i + 4);
  bf16x8 o;
  o[0] = (bf16)a.x; o[1] = (bf16)a.y; o[2] = (bf16)a.z; o[3] = (bf16)a.w;
  o[4] = (bf16)b.x; o[5] = (bf16)b.y; o[6] = (bf16)b.z; o[7] = (bf16)b.w;
  *(bf16x8*)(dst + i) = o;
}

// -------------------------------------------------------------------------
// NT-GEMM core: C[8192x1024] = A[8192x1024] * W[1024x1024]^T, bf16 in, f32 acc
// m97-style: 128x128 tile, BK=64, 256 thr (4 waves, 2x2 over tile, 64x64/wave),
// global_load_lds width=16 staging (LDS layout = lane deposit order).
// -------------------------------------------------------------------------
__device__ __forceinline__ void gemm_tile_compute(
    const bf16* __restrict__ A, const bf16* __restrict__ W,
    bf16* As, bf16* Bs, int m0, int n0, f32x4 acc[4][4])
{
  const int tid  = threadIdx.x;
  const int w    = tid >> 6;        // wave 0..3
  const int l    = tid & 63;
  const int quad = l >> 4;          // 0..3
  const int arow = l & 15;
  const int lrow = tid >> 3;        // 0..31 (row within 32-row staging slab)
  const int lcol = (tid & 7) * 8;   // 0..56
  const int wm = w >> 1, wn = w & 1;

  for (int kt = 0; kt < C_; kt += 64) {
    __syncthreads();                // previous tile fully consumed
#pragma unroll
    for (int i = 0; i < 4; i++) {
      const bf16* ga = A + (size_t)(m0 + i * 32 + lrow) * C_ + kt + lcol;
      __builtin_amdgcn_global_load_lds((AS1 unsigned int*)ga,
          (AS3 unsigned int*)(As + i * 2048 + w * 512), 16, 0, 0);
      const bf16* gb = W + (size_t)(n0 + i * 32 + lrow) * C_ + kt + lcol;
      __builtin_amdgcn_global_load_lds((AS1 unsigned int*)gb,
          (AS3 unsigned int*)(Bs + i * 2048 + w * 512), 16, 0, 0);
    }
    __syncthreads();                // drain vmcnt -> LDS tile ready

#pragma unroll
    for (int ks = 0; ks < 2; ks++) {
      bf16x8 af[4], bfr[4];
#pragma unroll
      for (int mt = 0; mt < 4; mt++)
        af[mt] = *(const bf16x8*)(As + (wm * 64 + mt * 16 + arow) * 64 + ks * 32 + quad * 8);
#pragma unroll
      for (int nt = 0; nt < 4; nt++)
        bfr[nt] = *(const bf16x8*)(Bs + (wn * 64 + nt * 16 + arow) * 64 + ks * 32 + quad * 8);
#pragma unroll
      for (int mt = 0; mt < 4; mt++)
#pragma unroll
        for (int nt = 0; nt < 4; nt++)
          acc[mt][nt] = __builtin_amdgcn_mfma_f32_16x16x32_bf16(af[mt], bfr[nt], acc[mt][nt], 0, 0, 0);
    }
  }
}

// QKV GEMM: z in {0,1,2} selects Wq/Wk/Wv; epilogue writes bf16 in (B,H,T,D)
__global__ __launch_bounds__(256) void gemm_qkv(
    const bf16* __restrict__ xb, const bf16* __restrict__ wb,
    bf16* __restrict__ qh, bf16* __restrict__ kh, bf16* __restrict__ vh)
{
  __shared__ bf16 As[128 * 64];
  __shared__ bf16 Bs[128 * 64];
  const int z = blockIdx.z;
  const bf16* W = wb + (size_t)z * (C_ * C_);
  bf16* out = (z == 0) ? qh : (z == 1) ? kh : vh;
  const int m0 = blockIdx.y * 128, n0 = blockIdx.x * 128;

  f32x4 acc[4][4];
#pragma unroll
  for (int i = 0; i < 4; i++)
#pragma unroll
    for (int j = 0; j < 4; j++) acc[i][j] = (f32x4){0.f, 0.f, 0.f, 0.f};

  gemm_tile_compute(xb, W, As, Bs, m0, n0, acc);

  const int tid = threadIdx.x, w = tid >> 6, l = tid & 63;
  const int quad = l >> 4, lc = l & 15, wm = w >> 1, wn = w & 1;
#pragma unroll
  for (int mt = 0; mt < 4; mt++) {
#pragma unroll
    for (int nt = 0; nt < 4; nt++) {
      const int col = n0 + wn * 64 + nt * 16 + lc;
      const int h = col >> 7, d = col & 127;
#pragma unroll
      for (int r = 0; r < 4; r++) {
        const int row = m0 + wm * 64 + mt * 16 + quad * 4 + r;
        const int b = row >> 11, t = row & 2047;
        out[(((size_t)(b * H_ + h)) * T_ + t) * D_ + d] = (bf16)acc[mt][nt][r];
      }
    }
  }
}

// Proj GEMM: plain f32 row-major epilogue into d_out
__global__ __launch_bounds__(256) void gemm_proj(
    const bf16* __restrict__ yb, const bf16* __restrict__ wproj, float* __restrict__ out)
{
  __shared__ bf16 As[128 * 64];
  __shared__ bf16 Bs[128 * 64];
  const int m0 = blockIdx.y * 128, n0 = blockIdx.x * 128;

  f32x4 acc[4][4];
#pragma unroll
  for (int i = 0; i < 4; i++)
#pragma unroll
    for (int j = 0; j < 4; j++) acc[i][j] = (f32x4){0.f, 0.f, 0.f, 0.f};

  gemm_tile_compute(yb, wproj, As, Bs, m0, n0, acc);

  const int tid = threadIdx.x, w = tid >> 6, l = tid & 63;
  const int quad = l >> 4, lc = l & 15, wm = w >> 1, wn = w & 1;
#pragma unroll
  for (int mt = 0; mt < 4; mt++) {
#pragma unroll
    for (int nt = 0; nt < 4; nt++) {
      const int col = n0 + wn * 64 + nt * 16 + lc;
#pragma unroll
      for (int r = 0; r < 4; r++) {
        const int row = m0 + wm * 64 + mt * 16 + quad * 4 + r;
        out[(size_t)row * C_ + col] = acc[mt][nt][r];
      }
    }
  }
}

// -------------------------------------------------------------------------
// rope + rmsnorm (q,k, in-place, fold D^-0.5 into q) + gate*ve add into v.
// One wave per (b,h,t) row; lane l owns dims l and l+64.
// -------------------------------------------------------------------------
__global__ __launch_bounds__(256) void rope_rms_gate(
    bf16* __restrict__ qh, bf16* __restrict__ kh, bf16* __restrict__ vh,
    const float* __restrict__ x, const float* __restrict__ ve,
    const float* __restrict__ cosb, const float* __restrict__ sinb,
    const float* __restrict__ wg)
{
  const int tid = threadIdx.x, w = tid >> 6, l = tid & 63;
  const int rq = blockIdx.x * 4 + w;           // ((b*H+h)*T + t)
  const int b = rq >> 14, h = (rq >> 11) & 7, t = rq & 2047;
  const float cv = cosb[t * 64 + l], sv = sinb[t * 64 + l];
  const float eps = 1.1920929e-07f;

  // ---- q: rope -> rmsnorm -> * D^-0.5 ----
  bf16* qr = qh + (size_t)rq * D_;
  float x1 = (float)qr[l], x2 = (float)qr[l + 64];
  float o1 = x1 * cv + x2 * sv;
  float o2 = x2 * cv - x1 * sv;
  float ss = o1 * o1 + o2 * o2;
#pragma unroll
  for (int off = 32; off; off >>= 1) ss += __shfl_xor(ss, off);
  float sc = rsqrtf(ss * (1.0f / 128.0f) + eps) * 0.08838834764831845f;
  qr[l] = (bf16)(o1 * sc); qr[l + 64] = (bf16)(o2 * sc);

  // ---- k: rope -> rmsnorm ----
  bf16* kr = kh + (size_t)rq * D_;
  x1 = (float)kr[l]; x2 = (float)kr[l + 64];
  o1 = x1 * cv + x2 * sv;
  o2 = x2 * cv - x1 * sv;
  ss = o1 * o1 + o2 * o2;
#pragma unroll
  for (int off = 32; off; off >>= 1) ss += __shfl_xor(ss, off);
  sc = rsqrtf(ss * (1.0f / 128.0f) + eps);
  kr[l] = (bf16)(o1 * sc); kr[l + 64] = (bf16)(o2 * sc);

  // ---- v += 2*sigmoid(x[:32]@Wg[h]) * ve ----
  const float* xr = x + ((size_t)(b * T_ + t)) * C_;
  float gp = (l < 32) ? xr[l] * wg[h * 32 + l] : 0.0f;
#pragma unroll
  for (int off = 32; off; off >>= 1) gp += __shfl_xor(gp, off);
  const float gate = 2.0f / (1.0f + __expf(-gp));
  bf16* vr = vh + (size_t)rq * D_;
  const float* ver = ve + ((size_t)(b * T_ + t)) * C_ + h * D_;
  vr[l]      = (bf16)((float)vr[l]      + gate * ver[l]);
  vr[l + 64] = (bf16)((float)vr[l + 64] + gate * ver[l + 64]);
}

// -------------------------------------------------------------------------
// Sliding-window flash attention (VALU, f32). Block: 64 q-rows of one (b,h),
// 256 threads = 4 threads/row (part = 32 dims each). K/V staged 32 keys at a
// time into LDS as f32. Part-rotated dim order -> conflict-free LDS reads.
// -------------------------------------------------------------------------
__global__ __launch_bounds__(256) void attn_kernel(
    const bf16* __restrict__ qh, const bf16* __restrict__ kh,
    const bf16* __restrict__ vh, bf16* __restrict__ yb)
{
  __shared__ float Kf[32 * 128];
  __shared__ float Vf[32 * 128];
  const int bh = blockIdx.y;                 // b*H + h
  const int q0 = blockIdx.x * 64;
  const int tid = threadIdx.x;
  const int row = tid >> 2, part = tid & 3;
  const int rowglob = q0 + row;

  const bf16* qrow = qh + ((size_t)bh * T_ + rowglob) * D_;
  float qreg[32], o[32];
#pragma unroll
  for (int j8 = 0; j8 < 8; j8++) {
    const int dbase = part * 32 + (((j8 + part) & 7) << 2);
#pragma unroll
    for (int c = 0; c < 4; c++) {
      qreg[j8 * 4 + c] = (float)qrow[dbase + c];
      o[j8 * 4 + c] = 0.0f;
    }
  }
  float m = -1e30f, lsum = 0.0f;

  const int kt_lo = (q0 > 1023) ? ((q0 - 1023) >> 5) : 0;
  const int kt_hi = (q0 + 63) >> 5;
  const bf16* kbase = kh + (size_t)bh * T_ * D_;
  const bf16* vbase = vh + (size_t)bh * T_ * D_;

  for (int kt = kt_lo; kt <= kt_hi; kt++) {
    __syncthreads();
    // stage 32 keys x 128 dims of K and V (4096 bf16 each), convert to f32
    const bf16* kp = kbase + (size_t)kt * 32 * D_;
    const bf16* vp = vbase + (size_t)kt * 32 * D_;
#pragma unroll
    for (int g = 0; g < 2; g++) {
      const int idx = (g * 256 + tid) * 8;
      bf16x8 kv = *(const bf16x8*)(kp + idx);
      bf16x8 vv = *(const bf16x8*)(vp + idx);
      float4 ka, kb2, va, vb2;
      ka.x = (float)kv[0]; ka.y = (float)kv[1]; ka.z = (float)kv[2]; ka.w = (float)kv[3];
      kb2.x = (float)kv[4]; kb2.y = (float)kv[5]; kb2.z = (float)kv[6]; kb2.w = (float)kv[7];
      va.x = (float)vv[0]; va.y = (float)vv[1]; va.z = (float)vv[2]; va.w = (float)vv[3];
      vb2.x = (float)vv[4]; vb2.y = (float)vv[5]; vb2.z = (float)vv[6]; vb2.w = (float)vv[7];
      *(float4*)(Kf + idx) = ka; *(float4*)(Kf + idx + 4) = kb2;
      *(float4*)(Vf + idx) = va; *(float4*)(Vf + idx + 4) = vb2;
    }
    __syncthreads();

    const int ktbase = kt * 32;
    for (int k = 0; k < 32; k++) {
      const int kg = ktbase + k;
      const bool valid = (kg <= rowglob) && (kg > rowglob - WIN_);
      // score (this part's 32 dims), rotated order
      float s = 0.0f;
      const float* krow = Kf + k * 128 + part * 32;
#pragma unroll
      for (int j8 = 0; j8 < 8; j8++) {
        const int off = ((j8 + part) & 7) << 2;
        float4 kv = *(const float4*)(krow + off);
        s += qreg[j8 * 4 + 0] * kv.x + qreg[j8 * 4 + 1] * kv.y
           + qreg[j8 * 4 + 2] * kv.z + qreg[j8 * 4 + 3] * kv.w;
      }
      s += __shfl_xor(s, 1);
      s += __shfl_xor(s, 2);
      s = valid ? s : -1e30f;
      const float mnew  = fmaxf(m, s);
      const float alpha = __expf(m - mnew);
      const float p     = valid ? __expf(s - mnew) : 0.0f;
      lsum = lsum * alpha + p;
      m = mnew;
      const float* vrow = Vf + k * 128 + part * 32;
#pragma unroll
      for (int j8 = 0; j8 < 8; j8++) {
        const int off = ((j8 + part) & 7) << 2;
        float4 vv = *(const float4*)(vrow + off);
        o[j8 * 4 + 0] = o[j8 * 4 + 0] * alpha + p * vv.x;
        o[j8 * 4 + 1] = o[j8 * 4 + 1] * alpha + p * vv.y;
        o[j8 * 4 + 2] = o[j8 * 4 + 2] * alpha + p * vv.z;
        o[j8 * 4 + 3] = o[j8 * 4 + 3] * alpha + p * vv.w;
      }
    }
  }

  const float inv = 1.0f / lsum;
  const int b = bh >> 3, h = bh & 7;
  bf16* yrow = yb + ((size_t)(b * T_ + rowglob)) * C_ + h * D_ + part * 32;
#pragma unroll
  for (int j8 = 0; j8 < 8; j8++) {
    const int off = ((j8 + part) & 7) << 2;
#pragma unroll
    for (int c = 0; c < 4; c++) yrow[off + c] = (bf16)(o[j8 * 4 + c] * inv);
  }
}

// -------------------------------------------------------------------------
// Launcher. Workspace layout (bytes):
//   [0, 16M)      xb (bf16 x)          -- reused as yb after gemm_qkv
//   [16M, 24M)    wb (bf16 Wq,Wk,Wv,Wproj)
//   [24M+..)      qh, kh, vh (bf16, (B,H,T,D) each 16M)
// Total 75,497,472 bytes.
// -------------------------------------------------------------------------
extern "C" void kernel_launch(void* const* d_in, const int* in_sizes, int n_in,
                              void* d_out, int out_size, void* d_ws, size_t ws_size,
                              hipStream_t stream) {
  const float* x     = (const float*)d_in[0];
  const float* ve    = (const float*)d_in[1];
  const float* cosb  = (const float*)d_in[2];
  const float* sinb  = (const float*)d_in[3];
  const float* Wq    = (const float*)d_in[4];
  const float* Wk    = (const float*)d_in[5];
  const float* Wv    = (const float*)d_in[6];
  const float* Wproj = (const float*)d_in[7];
  const float* Wg    = (const float*)d_in[8];

  char* ws = (char*)d_ws;
  bf16* xb = (bf16*)ws;                        // 8,388,608 elems
  bf16* wb = (bf16*)(ws + 16777216);           // 4 x 1,048,576 elems
  bf16* qh = (bf16*)(ws + 25165824);
  bf16* kh = (bf16*)(ws + 41943040);
  bf16* vh = (bf16*)(ws + 58720256);
  bf16* yb = xb;                               // reuse: xb dead after gemm_qkv

  const int NX = B_ * T_ * C_;                 // 8,388,608
  const int NW = C_ * C_;                      // 1,048,576

  cvt_kernel<<<NX / 8 / 256, 256, 0, stream>>>(x, xb, NX);
  cvt_kernel<<<NW / 8 / 256, 256, 0, stream>>>(Wq,    wb,          NW);
  cvt_kernel<<<NW / 8 / 256, 256, 0, stream>>>(Wk,    wb + NW,     NW);
  cvt_kernel<<<NW / 8 / 256, 256, 0, stream>>>(Wv,    wb + 2 * NW, NW);
  cvt_kernel<<<NW / 8 / 256, 256, 0, stream>>>(Wproj, wb + 3 * NW, NW);

  gemm_qkv<<<dim3(C_ / 128, (B_ * T_) / 128, 3), 256, 0, stream>>>(xb, wb, qh, kh, vh);
  rope_rms_gate<<<(B_ * H_ * T_) / 4, 256, 0, stream>>>(qh, kh, vh, x, ve, cosb, sinb, Wg);
  attn_kernel<<<dim3(T_ / 64, B_ * H_), 256, 0, stream>>>(qh, kh, vh, yb);
  gemm_proj<<<dim3(C_ / 128, (B_ * T_) / 128), 256, 0, stream>>>(yb, wb + 3 * NW, (float*)d_out);
}

// Round 2
// 396.106 us; speedup vs baseline: 3.0870x; 3.0870x over previous
//
#include <hip/hip_runtime.h>
#include <cstdint>
#include <cstddef>

typedef __bf16 bf16;
typedef __bf16 bf16x8 __attribute__((ext_vector_type(8)));
typedef float  f32x4  __attribute__((ext_vector_type(4)));

#define AS1 __attribute__((address_space(1)))
#define AS3 __attribute__((address_space(3)))

#define B_ 4
#define T_ 2048
#define C_ 1024
#define H_ 8
#define D_ 128
#define WIN_ 1024
#define PS_ 72   // P-slab row stride in bf16: 144B, 16B-aligned, 2-way banks on A-frag read

// -------------------------------------------------------------------------
// f32 -> bf16 conversion (8 elems/thread, vectorized)
// -------------------------------------------------------------------------
__global__ void cvt_kernel(const float* __restrict__ src, bf16* __restrict__ dst, int n) {
  int i = (blockIdx.x * 256 + threadIdx.x) * 8;
  if (i >= n) return;
  float4 a = *(const float4*)(src + i);
  float4 b = *(const float4*)(src + i + 4);
  bf16x8 o;
  o[0] = (bf16)a.x; o[1] = (bf16)a.y; o[2] = (bf16)a.z; o[3] = (bf16)a.w;
  o[4] = (bf16)b.x; o[5] = (bf16)b.y; o[6] = (bf16)b.z; o[7] = (bf16)b.w;
  *(bf16x8*)(dst + i) = o;
}

// -------------------------------------------------------------------------
// NT-GEMM core (m97 recipe, verified in round 1)
// -------------------------------------------------------------------------
__device__ __forceinline__ void gemm_tile_compute(
    const bf16* __restrict__ A, const bf16* __restrict__ W,
    bf16* As, bf16* Bs, int m0, int n0, f32x4 acc[4][4])
{
  const int tid  = threadIdx.x;
  const int w    = tid >> 6;
  const int l    = tid & 63;
  const int quad = l >> 4;
  const int arow = l & 15;
  const int lrow = tid >> 3;
  const int lcol = (tid & 7) * 8;
  const int wm = w >> 1, wn = w & 1;

  for (int kt = 0; kt < C_; kt += 64) {
    __syncthreads();
#pragma unroll
    for (int i = 0; i < 4; i++) {
      const bf16* ga = A + (size_t)(m0 + i * 32 + lrow) * C_ + kt + lcol;
      __builtin_amdgcn_global_load_lds((AS1 unsigned int*)ga,
          (AS3 unsigned int*)(As + i * 2048 + w * 512), 16, 0, 0);
      const bf16* gb = W + (size_t)(n0 + i * 32 + lrow) * C_ + kt + lcol;
      __builtin_amdgcn_global_load_lds((AS1 unsigned int*)gb,
          (AS3 unsigned int*)(Bs + i * 2048 + w * 512), 16, 0, 0);
    }
    __syncthreads();

#pragma unroll
    for (int ks = 0; ks < 2; ks++) {
      bf16x8 af[4], bfr[4];
#pragma unroll
      for (int mt = 0; mt < 4; mt++)
        af[mt] = *(const bf16x8*)(As + (wm * 64 + mt * 16 + arow) * 64 + ks * 32 + quad * 8);
#pragma unroll
      for (int nt = 0; nt < 4; nt++)
        bfr[nt] = *(const bf16x8*)(Bs + (wn * 64 + nt * 16 + arow) * 64 + ks * 32 + quad * 8);
#pragma unroll
      for (int mt = 0; mt < 4; mt++)
#pragma unroll
        for (int nt = 0; nt < 4; nt++)
          acc[mt][nt] = __builtin_amdgcn_mfma_f32_16x16x32_bf16(af[mt], bfr[nt], acc[mt][nt], 0, 0, 0);
    }
  }
}

__global__ __launch_bounds__(256) void gemm_qkv(
    const bf16* __restrict__ xb, const bf16* __restrict__ wb,
    bf16* __restrict__ qh, bf16* __restrict__ kh, bf16* __restrict__ vh)
{
  __shared__ bf16 As[128 * 64];
  __shared__ bf16 Bs[128 * 64];
  const int z = blockIdx.z;
  const bf16* W = wb + (size_t)z * (C_ * C_);
  bf16* out = (z == 0) ? qh : (z == 1) ? kh : vh;
  const int m0 = blockIdx.y * 128, n0 = blockIdx.x * 128;

  f32x4 acc[4][4];
#pragma unroll
  for (int i = 0; i < 4; i++)
#pragma unroll
    for (int j = 0; j < 4; j++) acc[i][j] = (f32x4){0.f, 0.f, 0.f, 0.f};

  gemm_tile_compute(xb, W, As, Bs, m0, n0, acc);

  const int tid = threadIdx.x, w = tid >> 6, l = tid & 63;
  const int quad = l >> 4, lc = l & 15, wm = w >> 1, wn = w & 1;
#pragma unroll
  for (int mt = 0; mt < 4; mt++) {
#pragma unroll
    for (int nt = 0; nt < 4; nt++) {
      const int col = n0 + wn * 64 + nt * 16 + lc;
      const int h = col >> 7, d = col & 127;
#pragma unroll
      for (int r = 0; r < 4; r++) {
        const int row = m0 + wm * 64 + mt * 16 + quad * 4 + r;
        const int b = row >> 11, t = row & 2047;
        out[(((size_t)(b * H_ + h)) * T_ + t) * D_ + d] = (bf16)acc[mt][nt][r];
      }
    }
  }
}

__global__ __launch_bounds__(256) void gemm_proj(
    const bf16* __restrict__ yb, const bf16* __restrict__ wproj, float* __restrict__ out)
{
  __shared__ bf16 As[128 * 64];
  __shared__ bf16 Bs[128 * 64];
  const int m0 = blockIdx.y * 128, n0 = blockIdx.x * 128;

  f32x4 acc[4][4];
#pragma unroll
  for (int i = 0; i < 4; i++)
#pragma unroll
    for (int j = 0; j < 4; j++) acc[i][j] = (f32x4){0.f, 0.f, 0.f, 0.f};

  gemm_tile_compute(yb, wproj, As, Bs, m0, n0, acc);

  const int tid = threadIdx.x, w = tid >> 6, l = tid & 63;
  const int quad = l >> 4, lc = l & 15, wm = w >> 1, wn = w & 1;
#pragma unroll
  for (int mt = 0; mt < 4; mt++) {
#pragma unroll
    for (int nt = 0; nt < 4; nt++) {
      const int col = n0 + wn * 64 + nt * 16 + lc;
#pragma unroll
      for (int r = 0; r < 4; r++) {
        const int row = m0 + wm * 64 + mt * 16 + quad * 4 + r;
        out[(size_t)row * C_ + col] = acc[mt][nt][r];
      }
    }
  }
}

// -------------------------------------------------------------------------
// rope + rmsnorm (q: fold D^-0.5 * log2(e) for exp2-domain softmax; k: plain)
// + gate*ve add into v. One wave per (b,h,t) row.
// -------------------------------------------------------------------------
__global__ __launch_bounds__(256) void rope_rms_gate(
    bf16* __restrict__ qh, bf16* __restrict__ kh, bf16* __restrict__ vh,
    const float* __restrict__ x, const float* __restrict__ ve,
    const float* __restrict__ cosb, const float* __restrict__ sinb,
    const float* __restrict__ wg)
{
  const int tid = threadIdx.x, w = tid >> 6, l = tid & 63;
  const int rq = blockIdx.x * 4 + w;           // ((b*H+h)*T + t)
  const int b = rq >> 14, h = (rq >> 11) & 7, t = rq & 2047;
  const float cv = cosb[t * 64 + l], sv = sinb[t * 64 + l];
  const float eps = 1.1920929e-07f;
  const float QSC = 0.08838834764831845f * 1.4426950408889634f; // D^-0.5 * log2e

  bf16* qr = qh + (size_t)rq * D_;
  float x1 = (float)qr[l], x2 = (float)qr[l + 64];
  float o1 = x1 * cv + x2 * sv;
  float o2 = x2 * cv - x1 * sv;
  float ss = o1 * o1 + o2 * o2;
#pragma unroll
  for (int off = 32; off; off >>= 1) ss += __shfl_xor(ss, off);
  float sc = rsqrtf(ss * (1.0f / 128.0f) + eps) * QSC;
  qr[l] = (bf16)(o1 * sc); qr[l + 64] = (bf16)(o2 * sc);

  bf16* kr = kh + (size_t)rq * D_;
  x1 = (float)kr[l]; x2 = (float)kr[l + 64];
  o1 = x1 * cv + x2 * sv;
  o2 = x2 * cv - x1 * sv;
  ss = o1 * o1 + o2 * o2;
#pragma unroll
  for (int off = 32; off; off >>= 1) ss += __shfl_xor(ss, off);
  sc = rsqrtf(ss * (1.0f / 128.0f) + eps);
  kr[l] = (bf16)(o1 * sc); kr[l + 64] = (bf16)(o2 * sc);

  const float* xr = x + ((size_t)(b * T_ + t)) * C_;
  float gp = (l < 32) ? xr[l] * wg[h * 32 + l] : 0.0f;
#pragma unroll
  for (int off = 32; off; off >>= 1) gp += __shfl_xor(gp, off);
  const float gate = 2.0f / (1.0f + __expf(-gp));
  bf16* vr = vh + (size_t)rq * D_;
  const float* ver = ve + ((size_t)(b * T_ + t)) * C_ + h * D_;
  vr[l]      = (bf16)((float)vr[l]      + gate * ver[l]);
  vr[l + 64] = (bf16)((float)vr[l + 64] + gate * ver[l + 64]);
}

// -------------------------------------------------------------------------
// V transpose: (B,H,T,D) -> (B,H,D,T), 64x64 tiles via f32 LDS (pad 65).
// -------------------------------------------------------------------------
__global__ __launch_bounds__(256) void transpose_v(
    const bf16* __restrict__ vh, bf16* __restrict__ vt)
{
  __shared__ float tile[64 * 65];
  const int bh = blockIdx.z;
  const int t0 = blockIdx.x * 64, d0 = blockIdx.y * 64;
  const int tid = threadIdx.x;
  const int r8 = tid >> 3, c8 = (tid & 7) * 8;
#pragma unroll
  for (int g = 0; g < 2; g++) {
    const int t = r8 + g * 32;
    bf16x8 v = *(const bf16x8*)(vh + ((size_t)bh * T_ + t0 + t) * D_ + d0 + c8);
#pragma unroll
    for (int j = 0; j < 8; j++) tile[t * 65 + c8 + j] = (float)v[j];
  }
  __syncthreads();
#pragma unroll
  for (int g = 0; g < 2; g++) {
    const int d = r8 + g * 32;
    bf16x8 o;
#pragma unroll
    for (int j = 0; j < 8; j++) o[j] = (bf16)tile[(c8 + j) * 65 + d];
    *(bf16x8*)(vt + ((size_t)bh * D_ + d0 + d) * T_ + t0 + c8) = o;
  }
}

// -------------------------------------------------------------------------
// MFMA flash attention (sliding window). Block: 128 q-rows of one (b,h),
// 4 waves x 32 rows. K-tile = 64 keys. Q frags in regs; K [k][d] and
// V^T [d][k] staged via global_load_lds; P round-trips through a
// wave-private LDS slab (C-layout -> A-layout).
// -------------------------------------------------------------------------
__global__ __launch_bounds__(256) void attn_mfma(
    const bf16* __restrict__ qh, const bf16* __restrict__ kh,
    const bf16* __restrict__ vt, bf16* __restrict__ yb)
{
  __shared__ bf16 Ks[64 * 128];    // [k][d]
  __shared__ bf16 VTs[128 * 64];   // [d][k]
  __shared__ bf16 Ps[4 * 32 * PS_];
  const int bh = blockIdx.y;
  const int q0 = blockIdx.x * 128;
  const int tid = threadIdx.x;
  const int w = tid >> 6, l = tid & 63;
  const int quad = l >> 4, l15 = l & 15;

  // Q A-frags [mt][dk], scale already folded in by rope_rms_gate
  bf16x8 qf[2][4];
  const bf16* qbase = qh + ((size_t)bh * T_ + q0 + w * 32 + l15) * D_;
#pragma unroll
  for (int mt = 0; mt < 2; mt++)
#pragma unroll
    for (int dk = 0; dk < 4; dk++)
      qf[mt][dk] = *(const bf16x8*)(qbase + mt * 16 * D_ + dk * 32 + quad * 8);

  f32x4 O[2][8];
  f32x4 mst[2], lst[2];
#pragma unroll
  for (int mt = 0; mt < 2; mt++) {
    mst[mt] = (f32x4){-3.0e38f, -3.0e38f, -3.0e38f, -3.0e38f};
    lst[mt] = (f32x4){0.f, 0.f, 0.f, 0.f};
#pragma unroll
    for (int dn = 0; dn < 8; dn++) O[mt][dn] = (f32x4){0.f, 0.f, 0.f, 0.f};
  }

  const int kt_lo = (q0 >= WIN_) ? ((q0 - (WIN_ - 1)) >> 6) : 0;
  const int kt_hi = (q0 + 127) >> 6;
  const bf16* kg = kh + (size_t)bh * T_ * D_;
  const bf16* vg = vt + (size_t)bh * D_ * T_;
  bf16* Pw = Ps + w * 32 * PS_;

  for (int kt = kt_lo; kt <= kt_hi; kt++) {
    const int k0 = kt * 64;
    __syncthreads();   // all waves done reading prev K/VT
#pragma unroll
    for (int s = 0; s < 4; s++) {
      // K tile: 16 k-rows/issue, 16 thr/row (128 d = 256B)
      const bf16* gk = kg + (size_t)(k0 + s * 16 + w * 4 + (l >> 4)) * D_ + l15 * 8;
      __builtin_amdgcn_global_load_lds((AS1 unsigned int*)gk,
          (AS3 unsigned int*)(Ks + s * 2048 + w * 512), 16, 0, 0);
      // VT tile: 32 d-rows/issue, 8 thr/row (64 k = 128B)
      const bf16* gv = vg + (size_t)(s * 32 + w * 8 + (l >> 3)) * T_ + k0 + (l & 7) * 8;
      __builtin_amdgcn_global_load_lds((AS1 unsigned int*)gv,
          (AS3 unsigned int*)(VTs + s * 2048 + w * 512), 16, 0, 0);
    }
    __syncthreads();   // staging complete

    // ---- S = Q K^T (C-layout: col=key=l15+nf*16, row=q=quad*4+r+mt*16) ----
    f32x4 sv[2][4];
#pragma unroll
    for (int mt = 0; mt < 2; mt++)
#pragma unroll
      for (int nf = 0; nf < 4; nf++) sv[mt][nf] = (f32x4){0.f, 0.f, 0.f, 0.f};
#pragma unroll
    for (int dk = 0; dk < 4; dk++) {
      bf16x8 kf[4];
#pragma unroll
      for (int nf = 0; nf < 4; nf++)
        kf[nf] = *(const bf16x8*)(Ks + (nf * 16 + l15) * 128 + dk * 32 + quad * 8);
#pragma unroll
      for (int mt = 0; mt < 2; mt++)
#pragma unroll
        for (int nf = 0; nf < 4; nf++)
          sv[mt][nf] = __builtin_amdgcn_mfma_f32_16x16x32_bf16(qf[mt][dk], kf[nf], sv[mt][nf], 0, 0, 0);
    }

    // ---- mask (causal + window) ----
#pragma unroll
    for (int mt = 0; mt < 2; mt++)
#pragma unroll
      for (int nf = 0; nf < 4; nf++) {
        const int kcol = k0 + nf * 16 + l15;
#pragma unroll
        for (int r = 0; r < 4; r++) {
          const int qrow = q0 + w * 32 + mt * 16 + quad * 4 + r;
          const bool ok = (kcol <= qrow) && (kcol > qrow - WIN_);
          sv[mt][nf][r] = ok ? sv[mt][nf][r] : -3.0e38f;
        }
      }

    // ---- online softmax (exp2 domain) + P write ----
#pragma unroll
    for (int mt = 0; mt < 2; mt++) {
      f32x4 rm = sv[mt][0];
#pragma unroll
      for (int nf = 1; nf < 4; nf++)
#pragma unroll
        for (int r = 0; r < 4; r++) rm[r] = fmaxf(rm[r], sv[mt][nf][r]);
#pragma unroll
      for (int off = 1; off < 16; off <<= 1)
#pragma unroll
        for (int r = 0; r < 4; r++) rm[r] = fmaxf(rm[r], __shfl_xor(rm[r], off));

      f32x4 mnew, alpha;
#pragma unroll
      for (int r = 0; r < 4; r++) {
        mnew[r] = fmaxf(mst[mt][r], rm[r]);
        alpha[r] = exp2f(mst[mt][r] - mnew[r]);
      }
      mst[mt] = mnew;

      f32x4 rs = (f32x4){0.f, 0.f, 0.f, 0.f};
#pragma unroll
      for (int nf = 0; nf < 4; nf++)
#pragma unroll
        for (int r = 0; r < 4; r++) {
          const float p = exp2f(sv[mt][nf][r] - mnew[r]);
          sv[mt][nf][r] = p;
          rs[r] += p;
        }
#pragma unroll
      for (int off = 1; off < 16; off <<= 1)
#pragma unroll
        for (int r = 0; r < 4; r++) rs[r] += __shfl_xor(rs[r], off);
#pragma unroll
      for (int r = 0; r < 4; r++) lst[mt][r] = lst[mt][r] * alpha[r] + rs[r];
#pragma unroll
      for (int dn = 0; dn < 8; dn++)
#pragma unroll
        for (int r = 0; r < 4; r++) O[mt][dn][r] *= alpha[r];

#pragma unroll
      for (int nf = 0; nf < 4; nf++)
#pragma unroll
        for (int r = 0; r < 4; r++)
          Pw[(mt * 16 + quad * 4 + r) * PS_ + nf * 16 + l15] = (bf16)sv[mt][nf][r];
    }

    __syncthreads();   // P C-layout writes -> A-layout reads (stop reordering)

    // ---- O += P V ----
#pragma unroll
    for (int ks = 0; ks < 2; ks++) {
      bf16x8 af0 = *(const bf16x8*)(Pw + l15 * PS_ + ks * 32 + quad * 8);
      bf16x8 af1 = *(const bf16x8*)(Pw + (16 + l15) * PS_ + ks * 32 + quad * 8);
#pragma unroll
      for (int dn = 0; dn < 8; dn++) {
        bf16x8 bfv = *(const bf16x8*)(VTs + (dn * 16 + l15) * 64 + ks * 32 + quad * 8);
        O[0][dn] = __builtin_amdgcn_mfma_f32_16x16x32_bf16(af0, bfv, O[0][dn], 0, 0, 0);
        O[1][dn] = __builtin_amdgcn_mfma_f32_16x16x32_bf16(af1, bfv, O[1][dn], 0, 0, 0);
      }
    }
  }

  // ---- epilogue: normalize, write y (B,T,C) ----
  const int b = bh >> 3, h = bh & 7;
#pragma unroll
  for (int mt = 0; mt < 2; mt++) {
    f32x4 inv;
#pragma unroll
    for (int r = 0; r < 4; r++) inv[r] = 1.0f / lst[mt][r];
#pragma unroll
    for (int dn = 0; dn < 8; dn++)
#pragma unroll
      for (int r = 0; r < 4; r++) {
        const int t = q0 + w * 32 + mt * 16 + quad * 4 + r;
        yb[((size_t)(b * T_ + t)) * C_ + h * D_ + dn * 16 + l15] = (bf16)(O[mt][dn][r] * inv[r]);
      }
  }
}

// -------------------------------------------------------------------------
// Launcher. ws layout (bytes), total 75,497,472:
//   [0,16M)    xb (x bf16)      -- dead after gemm_qkv, reused as vt
//   [16M,24M)  wb (4 weights)
//   [24M,40M)  qh   [40M,56M) kh   [56M,72M) vh -- vh dead after transpose,
//                                               reused as yb (attn out)
// -------------------------------------------------------------------------
extern "C" void kernel_launch(void* const* d_in, const int* in_sizes, int n_in,
                              void* d_out, int out_size, void* d_ws, size_t ws_size,
                              hipStream_t stream) {
  const float* x     = (const float*)d_in[0];
  const float* ve    = (const float*)d_in[1];
  const float* cosb  = (const float*)d_in[2];
  const float* sinb  = (const float*)d_in[3];
  const float* Wq    = (const float*)d_in[4];
  const float* Wk    = (const float*)d_in[5];
  const float* Wv    = (const float*)d_in[6];
  const float* Wproj = (const float*)d_in[7];
  const float* Wg    = (const float*)d_in[8];

  char* ws = (char*)d_ws;
  bf16* xb = (bf16*)ws;
  bf16* wb = (bf16*)(ws + 16777216);
  bf16* qh = (bf16*)(ws + 25165824);
  bf16* kh = (bf16*)(ws + 41943040);
  bf16* vh = (bf16*)(ws + 58720256);
  bf16* vtp = xb;     // reuse: xb dead after gemm_qkv
  bf16* yb = vh;      // reuse: vh dead after transpose_v

  const int NX = B_ * T_ * C_;
  const int NW = C_ * C_;

  cvt_kernel<<<NX / 8 / 256, 256, 0, stream>>>(x, xb, NX);
  cvt_kernel<<<NW / 8 / 256, 256, 0, stream>>>(Wq,    wb,          NW);
  cvt_kernel<<<NW / 8 / 256, 256, 0, stream>>>(Wk,    wb + NW,     NW);
  cvt_kernel<<<NW / 8 / 256, 256, 0, stream>>>(Wv,    wb + 2 * NW, NW);
  cvt_kernel<<<NW / 8 / 256, 256, 0, stream>>>(Wproj, wb + 3 * NW, NW);

  gemm_qkv<<<dim3(C_ / 128, (B_ * T_) / 128, 3), 256, 0, stream>>>(xb, wb, qh, kh, vh);
  rope_rms_gate<<<(B_ * H_ * T_) / 4, 256, 0, stream>>>(qh, kh, vh, x, ve, cosb, sinb, Wg);
  transpose_v<<<dim3(T_ / 64, D_ / 64, B_ * H_), 256, 0, stream>>>(vh, vtp);
  attn_mfma<<<dim3(T_ / 128, B_ * H_), 256, 0, stream>>>(qh, kh, vtp, yb);
  gemm_proj<<<dim3(C_ / 128, (B_ * T_) / 128), 256, 0, stream>>>(yb, wb + 3 * NW, (float*)d_out);
}

// Round 3
// 323.167 us; speedup vs baseline: 3.7838x; 1.2257x over previous
//
#include <hip/hip_runtime.h>
#include <cstdint>
#include <cstddef>

typedef __bf16 bf16;
typedef __bf16 bf16x8 __attribute__((ext_vector_type(8)));
typedef float  f32x4  __attribute__((ext_vector_type(4)));

#define AS1 __attribute__((address_space(1)))
#define AS3 __attribute__((address_space(3)))

#define B_ 4
#define T_ 2048
#define C_ 1024
#define H_ 8
#define D_ 128
#define WIN_ 1024
#define PS_ 72   // P-slab row stride (bf16): 144B -> bank-group (row+c)%8, conflict-free

// -------------------------------------------------------------------------
// f32 -> bf16 conversion (8 elems/thread, vectorized)
// -------------------------------------------------------------------------
__global__ void cvt_kernel(const float* __restrict__ src, bf16* __restrict__ dst, int n) {
  int i = (blockIdx.x * 256 + threadIdx.x) * 8;
  if (i >= n) return;
  float4 a = *(const float4*)(src + i);
  float4 b = *(const float4*)(src + i + 4);
  bf16x8 o;
  o[0] = (bf16)a.x; o[1] = (bf16)a.y; o[2] = (bf16)a.z; o[3] = (bf16)a.w;
  o[4] = (bf16)b.x; o[5] = (bf16)b.y; o[6] = (bf16)b.z; o[7] = (bf16)b.w;
  *(bf16x8*)(dst + i) = o;
}

// -------------------------------------------------------------------------
// NT-GEMM core (m97 recipe + XOR chunk swizzle: chunk c of row r lives at
// c ^ (r&7) -> frag reads spread over all 8 bank-groups, conflict-free).
// -------------------------------------------------------------------------
__device__ __forceinline__ void gemm_tile_compute(
    const bf16* __restrict__ A, const bf16* __restrict__ W,
    bf16* As, bf16* Bs, int m0, int n0, f32x4 acc[4][4])
{
  const int tid  = threadIdx.x;
  const int w    = tid >> 6;
  const int l    = tid & 63;
  const int quad = l >> 4;
  const int arow = l & 15;
  const int lrow = tid >> 3;                       // staging row in 32-row slab
  const int lcol = ((tid & 7) ^ (lrow & 7)) * 8;   // swizzled source chunk
  const int wm = w >> 1, wn = w & 1;
  const int sw = (arow & 7);                       // read-side swizzle key

  for (int kt = 0; kt < C_; kt += 64) {
    __syncthreads();
#pragma unroll
    for (int i = 0; i < 4; i++) {
      const bf16* ga = A + (size_t)(m0 + i * 32 + lrow) * C_ + kt + lcol;
      __builtin_amdgcn_global_load_lds((AS1 unsigned int*)ga,
          (AS3 unsigned int*)(As + i * 2048 + w * 512), 16, 0, 0);
      const bf16* gb = W + (size_t)(n0 + i * 32 + lrow) * C_ + kt + lcol;
      __builtin_amdgcn_global_load_lds((AS1 unsigned int*)gb,
          (AS3 unsigned int*)(Bs + i * 2048 + w * 512), 16, 0, 0);
    }
    __syncthreads();

#pragma unroll
    for (int ks = 0; ks < 2; ks++) {
      const int ch = ((ks * 4 + quad) ^ sw) * 8;   // swizzled chunk offset (elems)
      bf16x8 af[4], bfr[4];
#pragma unroll
      for (int mt = 0; mt < 4; mt++)
        af[mt] = *(const bf16x8*)(As + (wm * 64 + mt * 16 + arow) * 64 + ch);
#pragma unroll
      for (int nt = 0; nt < 4; nt++)
        bfr[nt] = *(const bf16x8*)(Bs + (wn * 64 + nt * 16 + arow) * 64 + ch);
#pragma unroll
      for (int mt = 0; mt < 4; mt++)
#pragma unroll
        for (int nt = 0; nt < 4; nt++)
          acc[mt][nt] = __builtin_amdgcn_mfma_f32_16x16x32_bf16(af[mt], bfr[nt], acc[mt][nt], 0, 0, 0);
    }
  }
}

__global__ __launch_bounds__(256) void gemm_qkv(
    const bf16* __restrict__ xb, const bf16* __restrict__ wb,
    bf16* __restrict__ qh, bf16* __restrict__ kh, bf16* __restrict__ vh)
{
  __shared__ bf16 As[128 * 64];
  __shared__ bf16 Bs[128 * 64];
  const int z = blockIdx.z;
  const bf16* W = wb + (size_t)z * (C_ * C_);
  bf16* out = (z == 0) ? qh : (z == 1) ? kh : vh;
  const int m0 = blockIdx.y * 128, n0 = blockIdx.x * 128;

  f32x4 acc[4][4];
#pragma unroll
  for (int i = 0; i < 4; i++)
#pragma unroll
    for (int j = 0; j < 4; j++) acc[i][j] = (f32x4){0.f, 0.f, 0.f, 0.f};

  gemm_tile_compute(xb, W, As, Bs, m0, n0, acc);

  const int tid = threadIdx.x, w = tid >> 6, l = tid & 63;
  const int quad = l >> 4, lc = l & 15, wm = w >> 1, wn = w & 1;
#pragma unroll
  for (int mt = 0; mt < 4; mt++) {
#pragma unroll
    for (int nt = 0; nt < 4; nt++) {
      const int col = n0 + wn * 64 + nt * 16 + lc;
      const int h = col >> 7, d = col & 127;
#pragma unroll
      for (int r = 0; r < 4; r++) {
        const int row = m0 + wm * 64 + mt * 16 + quad * 4 + r;
        const int b = row >> 11, t = row & 2047;
        out[(((size_t)(b * H_ + h)) * T_ + t) * D_ + d] = (bf16)acc[mt][nt][r];
      }
    }
  }
}

__global__ __launch_bounds__(256) void gemm_proj(
    const bf16* __restrict__ yb, const bf16* __restrict__ wproj, float* __restrict__ out)
{
  __shared__ bf16 As[128 * 64];
  __shared__ bf16 Bs[128 * 64];
  const int m0 = blockIdx.y * 128, n0 = blockIdx.x * 128;

  f32x4 acc[4][4];
#pragma unroll
  for (int i = 0; i < 4; i++)
#pragma unroll
    for (int j = 0; j < 4; j++) acc[i][j] = (f32x4){0.f, 0.f, 0.f, 0.f};

  gemm_tile_compute(yb, wproj, As, Bs, m0, n0, acc);

  const int tid = threadIdx.x, w = tid >> 6, l = tid & 63;
  const int quad = l >> 4, lc = l & 15, wm = w >> 1, wn = w & 1;
#pragma unroll
  for (int mt = 0; mt < 4; mt++) {
#pragma unroll
    for (int nt = 0; nt < 4; nt++) {
      const int col = n0 + wn * 64 + nt * 16 + lc;
#pragma unroll
      for (int r = 0; r < 4; r++) {
        const int row = m0 + wm * 64 + mt * 16 + quad * 4 + r;
        out[(size_t)row * C_ + col] = acc[mt][nt][r];
      }
    }
  }
}

// -------------------------------------------------------------------------
// rope + rmsnorm (q: fold D^-0.5 * log2(e) for exp2-domain softmax; k: plain)
// + gate*ve add into v. One wave per (b,h,t) row.
// -------------------------------------------------------------------------
__global__ __launch_bounds__(256) void rope_rms_gate(
    bf16* __restrict__ qh, bf16* __restrict__ kh, bf16* __restrict__ vh,
    const float* __restrict__ x, const float* __restrict__ ve,
    const float* __restrict__ cosb, const float* __restrict__ sinb,
    const float* __restrict__ wg)
{
  const int tid = threadIdx.x, w = tid >> 6, l = tid & 63;
  const int rq = blockIdx.x * 4 + w;           // ((b*H+h)*T + t)
  const int b = rq >> 14, h = (rq >> 11) & 7, t = rq & 2047;
  const float cv = cosb[t * 64 + l], sv = sinb[t * 64 + l];
  const float eps = 1.1920929e-07f;
  const float QSC = 0.08838834764831845f * 1.4426950408889634f; // D^-0.5 * log2e

  bf16* qr = qh + (size_t)rq * D_;
  float x1 = (float)qr[l], x2 = (float)qr[l + 64];
  float o1 = x1 * cv + x2 * sv;
  float o2 = x2 * cv - x1 * sv;
  float ss = o1 * o1 + o2 * o2;
#pragma unroll
  for (int off = 32; off; off >>= 1) ss += __shfl_xor(ss, off);
  float sc = rsqrtf(ss * (1.0f / 128.0f) + eps) * QSC;
  qr[l] = (bf16)(o1 * sc); qr[l + 64] = (bf16)(o2 * sc);

  bf16* kr = kh + (size_t)rq * D_;
  x1 = (float)kr[l]; x2 = (float)kr[l + 64];
  o1 = x1 * cv + x2 * sv;
  o2 = x2 * cv - x1 * sv;
  ss = o1 * o1 + o2 * o2;
#pragma unroll
  for (int off = 32; off; off >>= 1) ss += __shfl_xor(ss, off);
  sc = rsqrtf(ss * (1.0f / 128.0f) + eps);
  kr[l] = (bf16)(o1 * sc); kr[l + 64] = (bf16)(o2 * sc);

  const float* xr = x + ((size_t)(b * T_ + t)) * C_;
  float gp = (l < 32) ? xr[l] * wg[h * 32 + l] : 0.0f;
#pragma unroll
  for (int off = 32; off; off >>= 1) gp += __shfl_xor(gp, off);
  const float gate = 2.0f / (1.0f + __expf(-gp));
  bf16* vr = vh + (size_t)rq * D_;
  const float* ver = ve + ((size_t)(b * T_ + t)) * C_ + h * D_;
  vr[l]      = (bf16)((float)vr[l]      + gate * ver[l]);
  vr[l + 64] = (bf16)((float)vr[l + 64] + gate * ver[l + 64]);
}

// -------------------------------------------------------------------------
// V transpose: (B,H,T,D) -> (B,H,D,T), 64x64 tiles via f32 LDS (pad 65).
// -------------------------------------------------------------------------
__global__ __launch_bounds__(256) void transpose_v(
    const bf16* __restrict__ vh, bf16* __restrict__ vt)
{
  __shared__ float tile[64 * 65];
  const int bh = blockIdx.z;
  const int t0 = blockIdx.x * 64, d0 = blockIdx.y * 64;
  const int tid = threadIdx.x;
  const int r8 = tid >> 3, c8 = (tid & 7) * 8;
#pragma unroll
  for (int g = 0; g < 2; g++) {
    const int t = r8 + g * 32;
    bf16x8 v = *(const bf16x8*)(vh + ((size_t)bh * T_ + t0 + t) * D_ + d0 + c8);
#pragma unroll
    for (int j = 0; j < 8; j++) tile[t * 65 + c8 + j] = (float)v[j];
  }
  __syncthreads();
#pragma unroll
  for (int g = 0; g < 2; g++) {
    const int d = r8 + g * 32;
    bf16x8 o;
#pragma unroll
    for (int j = 0; j < 8; j++) o[j] = (bf16)tile[(c8 + j) * 65 + d];
    *(bf16x8*)(vt + ((size_t)bh * D_ + d0 + d) * T_ + t0 + c8) = o;
  }
}

// -------------------------------------------------------------------------
// MFMA flash attention, sliding window. 128 q-rows/block, 4 waves x 32 rows,
// 64-key tiles. Fixed-max softmax (score bound sqrt(D)*log2e = 16.32 from
// rmsnorm): no running max / alpha / O-rescale; row-sum is a per-lane partial
// reduced once at the end. K/VT staged with XOR chunk swizzle (bank-conflict
// free frag reads). P round-trips through a wave-private LDS slab.
// -------------------------------------------------------------------------
__global__ __launch_bounds__(256) void attn_mfma(
    const bf16* __restrict__ qh, const bf16* __restrict__ kh,
    const bf16* __restrict__ vt, bf16* __restrict__ yb)
{
  __shared__ bf16 Ks[64 * 128];    // [k][d], chunk-swizzled
  __shared__ bf16 VTs[128 * 64];   // [d][k], chunk-swizzled
  __shared__ bf16 Ps[4 * 32 * PS_];
  const int bh = blockIdx.y;
  const int q0 = blockIdx.x * 128;
  const int tid = threadIdx.x;
  const int w = tid >> 6, l = tid & 63;
  const int quad = l >> 4, l15 = l & 15;
  const int sw = l15 & 7;                    // read-side swizzle key
  const float FMAX = 16.5f;                  // fixed softmax max (exp2 domain)

  // Q A-frags (scale folded in by rope_rms_gate)
  bf16x8 qf[2][4];
  const bf16* qbase = qh + ((size_t)bh * T_ + q0 + w * 32 + l15) * D_;
#pragma unroll
  for (int mt = 0; mt < 2; mt++)
#pragma unroll
    for (int dk = 0; dk < 4; dk++)
      qf[mt][dk] = *(const bf16x8*)(qbase + mt * 16 * D_ + dk * 32 + quad * 8);

  f32x4 O[2][8];
  f32x4 lst[2];
#pragma unroll
  for (int mt = 0; mt < 2; mt++) {
    lst[mt] = (f32x4){0.f, 0.f, 0.f, 0.f};
#pragma unroll
    for (int dn = 0; dn < 8; dn++) O[mt][dn] = (f32x4){0.f, 0.f, 0.f, 0.f};
  }

  const int kt_lo = (q0 >= WIN_) ? ((q0 - (WIN_ - 1)) >> 6) : 0;
  const int kt_hi = (q0 + 127) >> 6;
  const bf16* kg = kh + (size_t)bh * T_ * D_;
  const bf16* vg = vt + (size_t)bh * D_ * T_;
  bf16* Pw = Ps + w * 32 * PS_;

  // staging source swizzle (lane-constant)
  const int krow_s = w * 4 + (l >> 4);                 // K stage row (mod 16)
  const int kcol_s = (l15 ^ (krow_s & 7)) * 8;
  const int vrow_s = w * 8 + (l >> 3);                 // VT stage row (mod 32)
  const int vcol_s = (((l & 7) ^ (vrow_s & 7))) * 8;

  for (int kt = kt_lo; kt <= kt_hi; kt++) {
    const int k0 = kt * 64;
    __syncthreads();   // all waves done reading prev K/VT
#pragma unroll
    for (int s = 0; s < 4; s++) {
      const bf16* gk = kg + (size_t)(k0 + s * 16 + krow_s) * D_ + kcol_s;
      __builtin_amdgcn_global_load_lds((AS1 unsigned int*)gk,
          (AS3 unsigned int*)(Ks + s * 2048 + w * 512), 16, 0, 0);
      const bf16* gv = vg + (size_t)(s * 32 + vrow_s) * T_ + k0 + vcol_s;
      __builtin_amdgcn_global_load_lds((AS1 unsigned int*)gv,
          (AS3 unsigned int*)(VTs + s * 2048 + w * 512), 16, 0, 0);
    }
    __syncthreads();   // staging complete

    // ---- S = Q K^T ----
    f32x4 sv[2][4];
#pragma unroll
    for (int mt = 0; mt < 2; mt++)
#pragma unroll
      for (int nf = 0; nf < 4; nf++) sv[mt][nf] = (f32x4){0.f, 0.f, 0.f, 0.f};
#pragma unroll
    for (int dk = 0; dk < 4; dk++) {
      const int ch = ((dk * 4 + quad) ^ sw) * 8;
      bf16x8 kf[4];
#pragma unroll
      for (int nf = 0; nf < 4; nf++)
        kf[nf] = *(const bf16x8*)(Ks + (nf * 16 + l15) * 128 + ch);
#pragma unroll
      for (int mt = 0; mt < 2; mt++)
#pragma unroll
        for (int nf = 0; nf < 4; nf++)
          sv[mt][nf] = __builtin_amdgcn_mfma_f32_16x16x32_bf16(qf[mt][dk], kf[nf], sv[mt][nf], 0, 0, 0);
    }

    // ---- mask only boundary tiles (block-uniform branch) ----
    if (!((k0 + 63 <= q0) && (k0 >= q0 + 128 - WIN_))) {
#pragma unroll
      for (int mt = 0; mt < 2; mt++)
#pragma unroll
        for (int nf = 0; nf < 4; nf++) {
          const int kcol = k0 + nf * 16 + l15;
#pragma unroll
          for (int r = 0; r < 4; r++) {
            const int qrow = q0 + w * 32 + mt * 16 + quad * 4 + r;
            const bool ok = (kcol <= qrow) && (kcol > qrow - WIN_);
            sv[mt][nf][r] = ok ? sv[mt][nf][r] : -3.0e38f;
          }
        }
    }

    // ---- fixed-max softmax: p = exp2(s - FMAX); per-lane partial row sums ----
#pragma unroll
    for (int mt = 0; mt < 2; mt++) {
#pragma unroll
      for (int nf = 0; nf < 4; nf++)
#pragma unroll
        for (int r = 0; r < 4; r++) {
          const float p = __builtin_amdgcn_exp2f(sv[mt][nf][r] - FMAX);
          sv[mt][nf][r] = p;
          lst[mt][r] += p;
        }
#pragma unroll
      for (int nf = 0; nf < 4; nf++)
#pragma unroll
        for (int r = 0; r < 4; r++)
          Pw[(mt * 16 + quad * 4 + r) * PS_ + nf * 16 + l15] = (bf16)sv[mt][nf][r];
    }

    asm volatile("" ::: "memory");  // order P writes before P reads (wave-private slab)

    // ---- O += P V ----
#pragma unroll
    for (int ks = 0; ks < 2; ks++) {
      const int ch = ((ks * 4 + quad) ^ sw) * 8;
      bf16x8 af0 = *(const bf16x8*)(Pw + l15 * PS_ + ks * 32 + quad * 8);
      bf16x8 af1 = *(const bf16x8*)(Pw + (16 + l15) * PS_ + ks * 32 + quad * 8);
#pragma unroll
      for (int dn = 0; dn < 8; dn++) {
        bf16x8 bfv = *(const bf16x8*)(VTs + (dn * 16 + l15) * 64 + ch);
        O[0][dn] = __builtin_amdgcn_mfma_f32_16x16x32_bf16(af0, bfv, O[0][dn], 0, 0, 0);
        O[1][dn] = __builtin_amdgcn_mfma_f32_16x16x32_bf16(af1, bfv, O[1][dn], 0, 0, 0);
      }
    }
  }

  // ---- final row-sum reduce (once) + epilogue ----
#pragma unroll
  for (int mt = 0; mt < 2; mt++)
#pragma unroll
    for (int off = 1; off < 16; off <<= 1)
#pragma unroll
      for (int r = 0; r < 4; r++) lst[mt][r] += __shfl_xor(lst[mt][r], off);

  const int b = bh >> 3, h = bh & 7;
#pragma unroll
  for (int mt = 0; mt < 2; mt++) {
    f32x4 inv;
#pragma unroll
    for (int r = 0; r < 4; r++) inv[r] = 1.0f / lst[mt][r];
#pragma unroll
    for (int dn = 0; dn < 8; dn++)
#pragma unroll
      for (int r = 0; r < 4; r++) {
        const int t = q0 + w * 32 + mt * 16 + quad * 4 + r;
        yb[((size_t)(b * T_ + t)) * C_ + h * D_ + dn * 16 + l15] = (bf16)(O[mt][dn][r] * inv[r]);
      }
  }
}

// -------------------------------------------------------------------------
// Launcher. ws layout (bytes), total 75,497,472:
//   [0,16M)    xb (x bf16)      -- dead after gemm_qkv, reused as vt
//   [16M,24M)  wb (4 weights)
//   [24M,40M)  qh   [40M,56M) kh   [56M,72M) vh -- vh dead after transpose,
//                                               reused as yb (attn out)
// -------------------------------------------------------------------------
extern "C" void kernel_launch(void* const* d_in, const int* in_sizes, int n_in,
                              void* d_out, int out_size, void* d_ws, size_t ws_size,
                              hipStream_t stream) {
  const float* x     = (const float*)d_in[0];
  const float* ve    = (const float*)d_in[1];
  const float* cosb  = (const float*)d_in[2];
  const float* sinb  = (const float*)d_in[3];
  const float* Wq    = (const float*)d_in[4];
  const float* Wk    = (const float*)d_in[5];
  const float* Wv    = (const float*)d_in[6];
  const float* Wproj = (const float*)d_in[7];
  const float* Wg    = (const float*)d_in[8];

  char* ws = (char*)d_ws;
  bf16* xb = (bf16*)ws;
  bf16* wb = (bf16*)(ws + 16777216);
  bf16* qh = (bf16*)(ws + 25165824);
  bf16* kh = (bf16*)(ws + 41943040);
  bf16* vh = (bf16*)(ws + 58720256);
  bf16* vtp = xb;     // reuse: xb dead after gemm_qkv
  bf16* yb = vh;      // reuse: vh dead after transpose_v

  const int NX = B_ * T_ * C_;
  const int NW = C_ * C_;

  cvt_kernel<<<NX / 8 / 256, 256, 0, stream>>>(x, xb, NX);
  cvt_kernel<<<NW / 8 / 256, 256, 0, stream>>>(Wq,    wb,          NW);
  cvt_kernel<<<NW / 8 / 256, 256, 0, stream>>>(Wk,    wb + NW,     NW);
  cvt_kernel<<<NW / 8 / 256, 256, 0, stream>>>(Wv,    wb + 2 * NW, NW);
  cvt_kernel<<<NW / 8 / 256, 256, 0, stream>>>(Wproj, wb + 3 * NW, NW);

  gemm_qkv<<<dim3(C_ / 128, (B_ * T_) / 128, 3), 256, 0, stream>>>(xb, wb, qh, kh, vh);
  rope_rms_gate<<<(B_ * H_ * T_) / 4, 256, 0, stream>>>(qh, kh, vh, x, ve, cosb, sinb, Wg);
  transpose_v<<<dim3(T_ / 64, D_ / 64, B_ * H_), 256, 0, stream>>>(vh, vtp);
  attn_mfma<<<dim3(T_ / 128, B_ * H_), 256, 0, stream>>>(qh, kh, vtp, yb);
  gemm_proj<<<dim3(C_ / 128, (B_ * T_) / 128), 256, 0, stream>>>(yb, wb + 3 * NW, (float*)d_out);
}